// Round 12
// baseline (196.041 us; speedup 1.0000x reference)
//
#include <hip/hip_runtime.h>

#define D     2048
#define BLK   512
#define EPSV  1e-5f

typedef short  s16x8 __attribute__((ext_vector_type(8)));
typedef float  f32x4 __attribute__((ext_vector_type(4)));

// pack two f32 -> packed bf16 (RNE); low = first arg
__device__ __forceinline__ unsigned int pk2(float x, float y) {
    unsigned int r;
    asm volatile("v_cvt_pk_bf16_f32 %0, %1, %2" : "=v"(r) : "v"(x), "v"(y));
    return r;
}
// decode packed bf16 pair
__device__ __forceinline__ float bl(unsigned int u) {
    union { unsigned int x; float f; } v; v.x = u << 16; return v.f;
}
__device__ __forceinline__ float bh(unsigned int u) {
    union { unsigned int x; float f; } v; v.x = u & 0xffff0000u; return v.f;
}

// DPP row_shr:N add (old=0)
template<int CTRL>
__device__ __forceinline__ float dppadd(float x) {
    int y = __builtin_amdgcn_update_dpp(0, __builtin_bit_cast(int, x), CTRL, 0xf, 0xf, false);
    return x + __builtin_bit_cast(float, y);
}
// full wave64 sum; result valid in lanes 15,31,47,63
__device__ __forceinline__ float wave_sum(float x) {
    x += __shfl_xor(x, 32, 64);
    x += __shfl_xor(x, 16, 64);
    x = dppadd<0x111>(x);
    x = dppadd<0x112>(x);
    x = dppadd<0x114>(x);
    x = dppadd<0x118>(x);
    return x;
}

__device__ __forceinline__ float rdlane(float v, int l) {
    return __builtin_bit_cast(float, __builtin_amdgcn_readlane(__builtin_bit_cast(int, v), l));
}

// ---- weight prep: Wq[c][p] = packed bf16 pair of column c at d={2p,2p+1}; S[c] = sum_d w[c][d]
// c: 0-3 Wb, 4-7 Wm, 8-23 Wr(i*4+j). Grid: 24 blocks x 256 threads.
__global__ __launch_bounds__(256) void wt_kernel(
    const float* __restrict__ Wb, const float* __restrict__ Wm,
    const float* __restrict__ Wr, unsigned int* __restrict__ Wq,
    float* __restrict__ S)
{
    const int c = blockIdx.x;
    const int t = threadIdx.x;
    const float* src;
    int stride;
    if (c < 4)       { src = Wb + c;       stride = 4;  }
    else if (c < 8)  { src = Wm + (c - 4); stride = 4;  }
    else             { src = Wr + (c - 8); stride = 16; }

    float s = 0.f;
    #pragma unroll
    for (int k = 0; k < 4; ++k) {
        int p = t + 256 * k;                    // pair index 0..1023
        float a = src[(2 * p)     * stride];
        float b = src[(2 * p + 1) * stride];
        s += a + b;
        Wq[c * 1024 + p] = pk2(a, b);
    }
    __shared__ float rsum[4];
    #pragma unroll
    for (int off = 32; off; off >>= 1) s += __shfl_xor(s, off, 64);
    if ((t & 63) == 0) rsum[t >> 6] = s;
    __syncthreads();
    if (t == 0) S[c] = rsum[0] + rsum[1] + rsum[2] + rsum[3];
}

__global__ __launch_bounds__(BLK) void hc_kernel(
    const float* __restrict__ lo,      // [tok, D]
    const float* __restrict__ hs,      // [tok, 4, D]
    const float* __restrict__ Bm,      // [1,4]
    const float* __restrict__ Am,      // [4,1]
    const float* __restrict__ Ar,      // [4,4]
    const float* __restrict__ s_alpha, // [4,4]
    const float* __restrict__ s_beta,  // [1,4]
    const unsigned int* __restrict__ Wq, // [24][1024] packed bf16 weight pairs
    const float* __restrict__ S,       // [24] column sums
    float* __restrict__ out)           // [tok, 4, D]
{
    // 1028 = 1024 + 4-uint row pad: shifts row base by 16B -> A-frag reads conflict-free
    __shared__ __align__(16) unsigned int hq[4][1028];   // ~16.4 KB bf16-packed hidden rows
    __shared__ float pred[8][24][4];       // per-wave MFMA partials R_w[c][n]
    __shared__ float sred[8][2];           // per-wave row-half {sum, sumsq}

    const int tid  = threadIdx.x;
    const int wave = tid >> 6;
    const int lane = tid & 63;
    const int row  = wave >> 1;            // P1: wave pair per hidden row
    const int half = wave & 1;
    const long tok = blockIdx.x;

    const float4* hs4  = (const float4*)(hs + tok * (long)(4 * D));
    const float4* lo4  = (const float4*)(lo + tok * (long)D);
    float4*       out4 = (float4*)(out + tok * (long)(4 * D));

    // ---- Phase 1: wave loads its half-row (lane-contiguous float4), stats + bf16 pack ----
    float4 hv[4];
    const int base = row * 512 + half * 256 + lane;
    #pragma unroll
    for (int k = 0; k < 4; ++k) hv[k] = hs4[base + 64 * k];
    float4 lv = lo4[tid];                  // used in phase 3

    float s = 0.f, q = 0.f;
    uint2* hq2w = (uint2*)hq[row];
    #pragma unroll
    for (int k = 0; k < 4; ++k) {
        float4 v = hv[k];
        s += v.x + v.y + v.z + v.w;
        q += v.x * v.x + v.y * v.y + v.z * v.z + v.w * v.w;
        uint2 p;
        p.x = pk2(v.x, v.y);
        p.y = pk2(v.z, v.w);
        hq2w[half * 256 + 64 * k + lane] = p;
    }
    s = wave_sum(s);
    q = wave_sum(q);
    if (lane == 15) { sred[wave][0] = s; sred[wave][1] = q; }
    __syncthreads();                       // bar1: hq + sred ready

    // ---- Phase 2: R[c][n] via MFMA. D[M=16 (h rows, 4 real)][N=16 (w cols/tile)], K split over waves.
    // A-frag: lane holds A[m=lane&15][k=(lane>>4)*8+j]  (m clamped &3 -> dup rows, D rows 4-15 unread)
    // B-frag: lane holds B[k=(lane>>4)*8+j][n=lane&15]  (= weight col, contiguous k in Wq)
    f32x4 acc0 = {0.f, 0.f, 0.f, 0.f};
    f32x4 acc1 = {0.f, 0.f, 0.f, 0.f};
    const int kg    = lane >> 4;           // k-group 0..3
    const int arow  = lane & 3;            // clamped h row
    const int bcol0 = lane & 15;           // tile0 col 0-15
    const int bcol1 = 16 + (lane & 7);     // tile1 col 16-23 (dup for lane&15>=8)
    const uint4* hqA = (const uint4*)hq[arow];
    const uint4* Wq4 = (const uint4*)Wq;   // [24][256] uint4 (8 bf16 each)

    #pragma unroll
    for (int st = 0; st < 8; ++st) {
        int idx = (wave * 8 + st) * 4 + kg;          // uint4 index along k
        s16x8 a  = __builtin_bit_cast(s16x8, hqA[idx]);
        s16x8 b0 = __builtin_bit_cast(s16x8, Wq4[bcol0 * 256 + idx]);
        s16x8 b1 = __builtin_bit_cast(s16x8, Wq4[bcol1 * 256 + idx]);
        acc0 = __builtin_amdgcn_mfma_f32_16x16x32_bf16(a, b0, acc0, 0, 0, 0);
        acc1 = __builtin_amdgcn_mfma_f32_16x16x32_bf16(a, b1, acc1, 0, 0, 0);
    }
    // useful D entries: lanes 0-15 (row group 0), reg r = h-row, lane = col-in-tile
    if (lane < 16) {
        #pragma unroll
        for (int r = 0; r < 4; ++r) pred[wave][lane][r] = acc0[r];
    }
    if (lane < 8) {
        #pragma unroll
        for (int r = 0; r < 4; ++r) pred[wave][16 + lane][r] = acc1[r];
    }
    __syncthreads();                       // bar2: pred + sred ready

    // ---- Combine (per-wave redundant; sums the 8 K-partials inline) ----
    float cv = 0.f;
    if (lane < 24) {
        int c = lane;
        float Sc = S[c];
        float raw = 0.f;
        #pragma unroll
        for (int n = 0; n < 4; ++n) {
            float R = 0.f;
            #pragma unroll
            for (int w = 0; w < 8; ++w) R += pred[w][c][n];
            float ss = sred[2 * n][0] + sred[2 * n + 1][0];
            float qq = sred[2 * n][1] + sred[2 * n + 1][1];
            float m   = ss * (1.f / D);
            float var = qq * (1.f / D) - m * m;
            float r   = rsqrtf(var + EPSV);
            raw += r * (R - m * Sc);
        }
        raw *= 0.25f;
        float t = tanhf(raw);
        if (c < 4) {
            cv = s_beta[c] * t + Bm[c];
        } else if (c < 8) {
            int n = c - 4;
            cv = s_alpha[n * 4] * t + Am[n];
        } else {
            int ij = c - 8;
            cv = s_alpha[ij] * t + Ar[ij];
        }
    }
    // broadcast through SGPRs
    float Bd[4], Amd[4], Ard[4][4];
    #pragma unroll
    for (int n = 0; n < 4; ++n) {
        Bd[n]  = rdlane(cv, n);
        Amd[n] = rdlane(cv, 4 + n);
    }
    #pragma unroll
    for (int i = 0; i < 4; ++i)
        #pragma unroll
        for (int j = 0; j < 4; ++j) Ard[i][j] = rdlane(cv, 8 + i * 4 + j);

    // ---- Phase 3: outputs; thread tid owns float4 d4 = tid ----
    float4 h[4];
    #pragma unroll
    for (int n = 0; n < 4; ++n) {
        uint2 r = ((const uint2*)hq[n])[tid];
        h[n].x = bl(r.x); h[n].y = bh(r.x);
        h[n].z = bl(r.y); h[n].w = bh(r.y);
    }
    float4 mx = {0.f, 0.f, 0.f, 0.f};
    #pragma unroll
    for (int n = 0; n < 4; ++n) {
        mx.x += Amd[n] * h[n].x; mx.y += Amd[n] * h[n].y;
        mx.z += Amd[n] * h[n].z; mx.w += Amd[n] * h[n].w;
    }
    #pragma unroll
    for (int i = 0; i < 4; ++i) {
        float4 o;
        o.x = Bd[i] * lv.x + mx.x;
        o.y = Bd[i] * lv.y + mx.y;
        o.z = Bd[i] * lv.z + mx.z;
        o.w = Bd[i] * lv.w + mx.w;
        #pragma unroll
        for (int j = 0; j < 4; ++j) {
            o.x += Ard[i][j] * h[j].x;
            o.y += Ard[i][j] * h[j].y;
            o.z += Ard[i][j] * h[j].z;
            o.w += Ard[i][j] * h[j].w;
        }
        out4[i * 512 + tid] = o;
    }
}

extern "C" void kernel_launch(void* const* d_in, const int* in_sizes, int n_in,
                              void* d_out, int out_size, void* d_ws, size_t ws_size,
                              hipStream_t stream) {
    const float* lo      = (const float*)d_in[0];
    const float* hs      = (const float*)d_in[1];
    const float* Bm      = (const float*)d_in[2];
    const float* Am      = (const float*)d_in[3];
    const float* Ar      = (const float*)d_in[4];
    const float* s_alpha = (const float*)d_in[5];
    const float* s_beta  = (const float*)d_in[6];
    const float* Wb      = (const float*)d_in[7];
    const float* Wm      = (const float*)d_in[8];
    const float* Wr      = (const float*)d_in[9];
    float* out = (float*)d_out;

    unsigned int* Wq = (unsigned int*)d_ws;                    // 98304 B
    float* S         = (float*)((char*)d_ws + 24 * 1024 * 4);  // 96 B

    wt_kernel<<<24, 256, 0, stream>>>(Wb, Wm, Wr, Wq, S);

    const int tokens = in_sizes[0] / D;            // 8192
    hc_kernel<<<tokens, BLK, 0, stream>>>(lo, hs, Bm, Am, Ar, s_alpha, s_beta,
                                          Wq, S, out);
}